// Round 5
// baseline (40.712 us; speedup 1.0000x reference)
//
#include <hip/hip_runtime.h>

// Problem: B=4, N=384, DX=2, DR=128, H=128, DOUT=64
// out[b,n,m,o] = relu( (x_ctx[b,n]-x_ctx[b,m]) @ W1[0:2] + r[b] @ W1[2:130] + b1 ) @ W2 + b2
//
// Round-5: 2-wave blocks, o-split across waves, cooperative stores.
//   - Block = one (b,n) row, 128 threads. Wave w computes o in [32w,32w+32)
//     for ALL m -> w2f shrinks 64->16 VGPRs -> total ~100 VGPR -> all
//     12 waves/CU resident in ONE generation (grid 1536 = 6 blocks/CU).
//   - Per super-iter: 2 m-tiles of 16. Each wave MFMAs its o-half, both
//     halves transposed into a shared 8KB LDS tile (XOR block swizzle,
//     uniform 8 dwords/bank on write AND read), 1 barrier, then 128
//     threads store 4 x 2KB fully-contiguous bursts (distinct rv regs
//     -> vmcnt waits at depth>=4, stores stay in flight).
//   - hf (h-preact) duplicated across the wave pair: +VALU, hidden by
//     occupancy; avoids LDS-BW-heavy h sharing.
//   - c[b,:] recomputed per block (identical arithmetic -> deterministic).

typedef __attribute__((ext_vector_type(8))) __bf16 bf16x8;
typedef __attribute__((ext_vector_type(4))) float f32x4;
typedef __attribute__((ext_vector_type(2))) float f32x2;

#define B_    4
#define N_    384
#define H_    128
#define DOUT_ 64

__global__ __launch_bounds__(128, 3) void te_fused(
    const float* __restrict__ r, const float* __restrict__ xctx,
    const float* __restrict__ W1, const float* __restrict__ b1,
    const float* __restrict__ W2, const float* __restrict__ b2,
    float* __restrict__ out)
{
    __shared__ __align__(16) float xs[N_ * 2];          // 3 KB   x_ctx[b]
    __shared__ __align__(16) float cs[H_];              // 0.5 KB c[b,:]
    __shared__ __align__(16) float tbuf[2][2][16][64];  // 16 KB  dbuf x 2 m-tiles

    const int tid  = threadIdx.x;
    const int w    = tid >> 6, lane = tid & 63;
    const int g    = lane >> 4, rl = lane & 15;

    const int bid = blockIdx.x;
    const int b = bid / N_, n = bid - b * N_;

    // ---- c[k] = b1[k] + sum_d r[b,d] * W1[2+d,k]  (thread k = tid) ----
    {
        float acc = b1[tid];
        const float* wc = W1 + 2 * H_ + tid;
        const float* rb = r + b * 128;
        #pragma unroll 8
        for (int d = 0; d < 128; ++d) acc = fmaf(rb[d], wc[d * H_], acc);
        cs[tid] = acc;
    }
    // ---- stage x_ctx[b]: 768 floats = 192 f32x4 ----
    {
        const float* xb = xctx + b * (N_ * 2);
        *reinterpret_cast<f32x4*>(&xs[tid * 4]) =
            *reinterpret_cast<const f32x4*>(xb + tid * 4);
        if (tid < 64)
            *reinterpret_cast<f32x4*>(&xs[(128 + tid) * 4]) =
                *reinterpret_cast<const f32x4*>(xb + (128 + tid) * 4);
    }

    // ---- W2^T fragments for this wave's o-slice [32w, 32w+32) ----
    // A-frag row = o_within_tile = rl; elem jj -> kk = ks*32+(jj>=4)*16+g*4+(jj&3)
    bf16x8 w2f[2][4];
    #pragma unroll
    for (int ot = 0; ot < 2; ++ot) {
        const float* wp = W2 + w * 32 + ot * 16 + rl;   // + kk*64
        #pragma unroll
        for (int ks = 0; ks < 4; ++ks)
            #pragma unroll
            for (int jj = 0; jj < 8; ++jj) {
                const int kk = ks * 32 + ((jj >> 2) << 4) + (g << 2) + (jj & 3);
                w2f[ot][ks][jj] = (__bf16)wp[kk * DOUT_];
            }
    }

    // ---- W1 row fragments + b2 fragments ----
    f32x4 w1a[4][2], w1b[4][2], cf[4][2], b2f[2];
    #pragma unroll
    for (int ks = 0; ks < 4; ++ks)
        #pragma unroll
        for (int hh = 0; hh < 2; ++hh) {
            const int kk = ks * 32 + hh * 16 + (g << 2);
            w1a[ks][hh] = *reinterpret_cast<const f32x4*>(W1 + kk);
            w1b[ks][hh] = *reinterpret_cast<const f32x4*>(W1 + H_ + kk);
        }
    #pragma unroll
    for (int ot = 0; ot < 2; ++ot)
        b2f[ot] = *reinterpret_cast<const f32x4*>(b2 + w * 32 + ot * 16 + (g << 2));

    __syncthreads();   // xs + cs ready

    #pragma unroll
    for (int ks = 0; ks < 4; ++ks)
        #pragma unroll
        for (int hh = 0; hh < 2; ++hh)
            cf[ks][hh] = *reinterpret_cast<const f32x4*>(&cs[ks * 32 + hh * 16 + (g << 2)]);

    const float x0n = xs[2 * n], x1n = xs[2 * n + 1];
    float* const outn = out + ((size_t)(b * N_ + n)) * N_ * DOUT_;
    const int ob2 = tid & 15;     // read-side 16B o-block
    const int mr0 = tid >> 4;     // read-side row 0..7

    // ---- main loop: 12 super-iters x 2 m-tiles of 16 ----
    for (int tp = 0; tp < 12; ++tp) {
        const int s = tp & 1;

        #pragma unroll
        for (int half = 0; half < 2; ++half) {
            const int m = tp * 32 + half * 16 + rl;
            const f32x2 xp = *reinterpret_cast<const f32x2*>(&xs[2 * m]);
            const float dx0 = x0n - xp[0], dx1 = x1n - xp[1];

            bf16x8 hf[4];
            #pragma unroll
            for (int ks = 0; ks < 4; ++ks)
                #pragma unroll
                for (int hh = 0; hh < 2; ++hh)
                    #pragma unroll
                    for (int j = 0; j < 4; ++j) {
                        float hp = fmaf(dx1, w1b[ks][hh][j],
                                   fmaf(dx0, w1a[ks][hh][j], cf[ks][hh][j]));
                        hf[ks][hh * 4 + j] = (__bf16)(hp > 0.f ? hp : 0.f);
                    }

            f32x4 acc0 = b2f[0], acc1 = b2f[1];
            #pragma unroll
            for (int ks = 0; ks < 4; ++ks) {
                acc0 = __builtin_amdgcn_mfma_f32_16x16x32_bf16(w2f[0][ks], hf[ks], acc0, 0, 0, 0);
                acc1 = __builtin_amdgcn_mfma_f32_16x16x32_bf16(w2f[1][ks], hf[ks], acc1, 0, 0, 0);
            }

            // transpose-write: D col=rl=m, rows o = w*32+ot*16+g*4+reg.
            // 16B-block index ob = w*8+ot*4+g, swizzled ob^rl (uniform banks).
            {
                const int ob0 = (w << 3) | g;
                *reinterpret_cast<f32x4*>(&tbuf[s][half][rl][(ob0 ^ rl) << 2]) = acc0;
                const int ob1 = (w << 3) | 4 | g;
                *reinterpret_cast<f32x4*>(&tbuf[s][half][rl][(ob1 ^ rl) << 2]) = acc1;
            }
        }

        __syncthreads();   // tile pair complete (dbuf: safe with 1 barrier/iter)

        // cooperative read + store: 4 passes x 2KB fully contiguous
        float* const onp = outn + (size_t)(tp * 32) * DOUT_;
        #pragma unroll
        for (int p = 0; p < 4; ++p) {
            const int sub = p >> 1;
            const int mr  = mr0 + ((p & 1) << 3);
            f32x4 rv = *reinterpret_cast<const f32x4*>(&tbuf[s][sub][mr][(ob2 ^ mr) << 2]);
            *reinterpret_cast<f32x4*>(onp + (size_t)(sub * 16 + mr) * DOUT_ + (ob2 << 2)) = rv;
        }
    }
}

extern "C" void kernel_launch(void* const* d_in, const int* in_sizes, int n_in,
                              void* d_out, int out_size, void* d_ws, size_t ws_size,
                              hipStream_t stream)
{
    const float* r    = (const float*)d_in[0];
    const float* xctx = (const float*)d_in[1];
    // d_in[2] = y_ctx (unused), d_in[3] = x_trg (unused)
    const float* W1 = (const float*)d_in[4];
    const float* b1 = (const float*)d_in[5];
    const float* W2 = (const float*)d_in[6];
    const float* b2 = (const float*)d_in[7];
    float* out = (float*)d_out;

    hipLaunchKernelGGL(te_fused, dim3(B_ * N_), dim3(128), 0, stream,
                       r, xctx, W1, b1, W2, b2, out);
}